// Round 1
// baseline (772.595 us; speedup 1.0000x reference)
//
#include <hip/hip_runtime.h>
#include <math.h>

namespace {
constexpr int N = 50000;
constexpr int E = 20000;
constexpr int NNZ = 800000;
constexpr int DIN = 128;
constexpr int HD = 256;   // H*DOUT

// workspace layout (floats)
constexpr size_t OFF_UVT = 0;                           // [4][128]
constexpr size_t OFF_UET = 512;                         // [4][128]
constexpr size_t OFF_EV  = 1024;                        // [N][4]
constexpr size_t OFF_EE  = OFF_EV  + (size_t)N * 4;     // [E][4]
constexpr size_t OFF_M   = OFF_EE  + (size_t)E * 4;     // [N][4]
constexpr size_t OFF_DEN = OFF_M   + (size_t)N * 4;     // [N][4]
constexpr size_t OFF_SX  = OFF_DEN + (size_t)N * 4;     // [NNZ][4]  s then ex
constexpr size_t OFF_COEF= OFF_SX  + (size_t)NNZ * 4;   // [NNZ]
constexpr size_t OFF_FT  = OFF_COEF+ (size_t)NNZ;       // [N][256]
}

// ---- kernel 1: u tables: u[h][k] = sum_d W_p[k, h*64+d] * attn[h,d] ----
__global__ void k_u(const float* __restrict__ Wp, const float* __restrict__ attn_v,
                    const float* __restrict__ attn_e,
                    float* __restrict__ uvT, float* __restrict__ ueT) {
    int t = threadIdx.x;
    for (int task = t; task < 1024; task += 256) {
        int which = task >> 9;            // 0: v-table, 1: e-table
        int hk = task & 511;
        int h = hk >> 7, k = hk & 127;
        const float* attn = which ? attn_e : attn_v;
        float s = 0.f;
        #pragma unroll 8
        for (int d = 0; d < 64; ++d)
            s += Wp[k * HD + h * 64 + d] * attn[h * 64 + d];
        (which ? ueT : uvT)[h * 128 + k] = s;
    }
}

// ---- kernel 2: e_v[n,h] = vfeat[n,:] . u_v[h,:];  e_e likewise (one wave/row)
__global__ void k_ev(const float* __restrict__ vfeat, const float* __restrict__ efeat,
                     const float* __restrict__ uvT, const float* __restrict__ ueT,
                     float* __restrict__ e_v, float* __restrict__ e_e) {
    __shared__ float su[2][4][128];
    int t = threadIdx.x;
    for (int idx = t; idx < 512; idx += 256) {
        su[0][0][idx] = uvT[idx];
        su[1][0][idx] = ueT[idx];
    }
    __syncthreads();
    int wave = t >> 6, lane = t & 63;
    int row = blockIdx.x * 4 + wave;
    if (row >= N + E) return;
    const float* feat; const float (*u)[128]; float* out; int r;
    if (row < N) { feat = vfeat; u = su[0]; out = e_v; r = row; }
    else         { feat = efeat; u = su[1]; out = e_e; r = row - N; }
    float f0 = feat[(size_t)r * DIN + lane];
    float f1 = feat[(size_t)r * DIN + 64 + lane];
    float p0 = f0 * u[0][lane] + f1 * u[0][64 + lane];
    float p1 = f0 * u[1][lane] + f1 * u[1][64 + lane];
    float p2 = f0 * u[2][lane] + f1 * u[2][64 + lane];
    float p3 = f0 * u[3][lane] + f1 * u[3][64 + lane];
    #pragma unroll
    for (int off = 32; off > 0; off >>= 1) {
        p0 += __shfl_xor(p0, off, 64);
        p1 += __shfl_xor(p1, off, 64);
        p2 += __shfl_xor(p2, off, 64);
        p3 += __shfl_xor(p3, off, 64);
    }
    if (lane == 0)
        *reinterpret_cast<float4*>(&out[(size_t)r * 4]) = make_float4(p0, p1, p2, p3);
}

// ---- kernel 3: ft = (vfeat @ W_v) * DV2, [N][256]; 64x64 tile SGEMM ----
__global__ __launch_bounds__(256) void k_ft(const float* __restrict__ vfeat,
                                            const float* __restrict__ Wv,
                                            const float* __restrict__ DV2,
                                            float* __restrict__ ft) {
    __shared__ float As[32][65];
    __shared__ float Bs[32][64];
    int tid = threadIdx.x;
    int rowBase = blockIdx.x * 64;
    int colBase = blockIdx.y * 64;
    int tx = tid & 15, ty = tid >> 4;
    int tx4 = tx * 4, ty4 = ty * 4;
    float acc[4][4] = {};
    for (int k0 = 0; k0 < DIN; k0 += 32) {
        #pragma unroll
        for (int i = 0; i < 2; ++i) {
            int e = tid + i * 256;        // 0..511
            int r = e >> 3;               // 0..63
            int k4 = e & 7;               // 0..7
            int row = rowBase + r;
            float4 v = make_float4(0.f, 0.f, 0.f, 0.f);
            if (row < N)
                v = *reinterpret_cast<const float4*>(&vfeat[(size_t)row * DIN + k0 + k4 * 4]);
            As[k4 * 4 + 0][r] = v.x;
            As[k4 * 4 + 1][r] = v.y;
            As[k4 * 4 + 2][r] = v.z;
            As[k4 * 4 + 3][r] = v.w;
        }
        #pragma unroll
        for (int i = 0; i < 2; ++i) {
            int e = tid + i * 256;
            int k = e >> 4;               // 0..31
            int c4 = e & 15;              // 0..15
            *reinterpret_cast<float4*>(&Bs[k][c4 * 4]) =
                *reinterpret_cast<const float4*>(&Wv[(size_t)(k0 + k) * HD + colBase + c4 * 4]);
        }
        __syncthreads();
        #pragma unroll 8
        for (int k = 0; k < 32; ++k) {
            float a0 = As[k][ty4 + 0], a1 = As[k][ty4 + 1];
            float a2 = As[k][ty4 + 2], a3 = As[k][ty4 + 3];
            float4 b = *reinterpret_cast<const float4*>(&Bs[k][tx4]);
            acc[0][0] += a0 * b.x; acc[0][1] += a0 * b.y; acc[0][2] += a0 * b.z; acc[0][3] += a0 * b.w;
            acc[1][0] += a1 * b.x; acc[1][1] += a1 * b.y; acc[1][2] += a1 * b.z; acc[1][3] += a1 * b.w;
            acc[2][0] += a2 * b.x; acc[2][1] += a2 * b.y; acc[2][2] += a2 * b.z; acc[2][3] += a2 * b.w;
            acc[3][0] += a3 * b.x; acc[3][1] += a3 * b.y; acc[3][2] += a3 * b.z; acc[3][3] += a3 * b.w;
        }
        __syncthreads();
    }
    #pragma unroll
    for (int mi = 0; mi < 4; ++mi) {
        int row = rowBase + ty4 + mi;
        if (row < N) {
            float dv = DV2[row];
            float4 o = make_float4(acc[mi][0] * dv, acc[mi][1] * dv,
                                   acc[mi][2] * dv, acc[mi][3] * dv);
            *reinterpret_cast<float4*>(&ft[(size_t)row * HD + colBase + tx4]) = o;
        }
    }
}

// ---- kernel 4: s = relu(e_e[e] + e_v[n]); atomicMax into m (float>=0 as uint)
__global__ void k_logits(const int* __restrict__ node_idx, const int* __restrict__ edge_idx,
                         const float* __restrict__ e_v, const float* __restrict__ e_e,
                         float* __restrict__ sx, unsigned int* __restrict__ m) {
    int i = blockIdx.x * 256 + threadIdx.x;
    if (i >= NNZ) return;
    int n = node_idx[i], e = edge_idx[i];
    float4 av = *reinterpret_cast<const float4*>(&e_v[(size_t)n * 4]);
    float4 ae = *reinterpret_cast<const float4*>(&e_e[(size_t)e * 4]);
    float4 s;
    s.x = fmaxf(av.x + ae.x, 0.f);
    s.y = fmaxf(av.y + ae.y, 0.f);
    s.z = fmaxf(av.z + ae.z, 0.f);
    s.w = fmaxf(av.w + ae.w, 0.f);
    *reinterpret_cast<float4*>(&sx[(size_t)i * 4]) = s;
    atomicMax(&m[(size_t)n * 4 + 0], __float_as_uint(s.x));
    atomicMax(&m[(size_t)n * 4 + 1], __float_as_uint(s.y));
    atomicMax(&m[(size_t)n * 4 + 2], __float_as_uint(s.z));
    atomicMax(&m[(size_t)n * 4 + 3], __float_as_uint(s.w));
}

// ---- kernel 5: ex = exp(s - m[n]); den[n] += ex (in-place over sx) ----
__global__ void k_expsum(const int* __restrict__ node_idx,
                         const float* __restrict__ m,
                         float* __restrict__ sx, float* __restrict__ den) {
    int i = blockIdx.x * 256 + threadIdx.x;
    if (i >= NNZ) return;
    int n = node_idx[i];
    float4 s = *reinterpret_cast<const float4*>(&sx[(size_t)i * 4]);
    float4 mm = *reinterpret_cast<const float4*>(&m[(size_t)n * 4]);
    float4 ex = make_float4(__expf(s.x - mm.x), __expf(s.y - mm.y),
                            __expf(s.z - mm.z), __expf(s.w - mm.w));
    *reinterpret_cast<float4*>(&sx[(size_t)i * 4]) = ex;
    atomicAdd(&den[(size_t)n * 4 + 0], ex.x);
    atomicAdd(&den[(size_t)n * 4 + 1], ex.y);
    atomicAdd(&den[(size_t)n * 4 + 2], ex.z);
    atomicAdd(&den[(size_t)n * 4 + 3], ex.w);
}

// ---- kernel 6: stage 1, one wave per incidence; lane = output dim ----
// efeat_out[e,d] += 0.25 * sum_h a[i,h] * ft[n, h*64+d]
// coef[i] = 0.25 * (sum_h a[i,h]) * invDE[e] * DV2[n]   (for stage 2)
__global__ void k_stage1(const int* __restrict__ node_idx, const int* __restrict__ edge_idx,
                         const float* __restrict__ sx, const float* __restrict__ den,
                         const float* __restrict__ ft, const float* __restrict__ invDE,
                         const float* __restrict__ DV2,
                         float* __restrict__ efeat_out, float* __restrict__ coef) {
    int i = (blockIdx.x << 2) + (threadIdx.x >> 6);
    int lane = threadIdx.x & 63;
    if (i >= NNZ) return;
    int n = node_idx[i], e = edge_idx[i];
    float4 ex = *reinterpret_cast<const float4*>(&sx[(size_t)i * 4]);
    float4 dn = *reinterpret_cast<const float4*>(&den[(size_t)n * 4]);
    float a0 = ex.x / dn.x, a1 = ex.y / dn.y, a2 = ex.z / dn.z, a3 = ex.w / dn.w;
    const float* ftr = &ft[(size_t)n * HD];
    float v = ftr[lane] * a0 + ftr[64 + lane] * a1 + ftr[128 + lane] * a2 + ftr[192 + lane] * a3;
    atomicAdd(&efeat_out[(size_t)e * 64 + lane], v * 0.25f);
    if (lane == 0)
        coef[i] = 0.25f * (a0 + a1 + a2 + a3) * invDE[e] * DV2[n];
}

// ---- kernel 7: stage 2: vfeat_out[n,d] += coef[i] * efeat_out[e,d] ----
__global__ void k_stage2(const int* __restrict__ node_idx, const int* __restrict__ edge_idx,
                         const float* __restrict__ efeat_out, const float* __restrict__ coef,
                         float* __restrict__ vfeat_out) {
    int i = (blockIdx.x << 2) + (threadIdx.x >> 6);
    int lane = threadIdx.x & 63;
    if (i >= NNZ) return;
    int n = node_idx[i], e = edge_idx[i];
    float c = coef[i];
    atomicAdd(&vfeat_out[(size_t)n * 64 + lane], efeat_out[(size_t)e * 64 + lane] * c);
}

extern "C" void kernel_launch(void* const* d_in, const int* in_sizes, int n_in,
                              void* d_out, int out_size, void* d_ws, size_t ws_size,
                              hipStream_t stream) {
    const float* vfeat   = (const float*)d_in[0];
    const float* efeat   = (const float*)d_in[1];
    const float* DV2     = (const float*)d_in[2];
    const float* invDE   = (const float*)d_in[3];
    const float* Wp      = (const float*)d_in[4];
    const float* Wv      = (const float*)d_in[5];
    const float* attn_v  = (const float*)d_in[6];
    const float* attn_e  = (const float*)d_in[7];
    const int* node_idx  = (const int*)d_in[8];
    const int* edge_idx  = (const int*)d_in[9];

    float* out  = (float*)d_out;
    float* vout = out;                       // [N][64]
    float* eout = out + (size_t)N * 64;      // [E][64]

    float* ws   = (float*)d_ws;
    float* uvT  = ws + OFF_UVT;
    float* ueT  = ws + OFF_UET;
    float* e_v  = ws + OFF_EV;
    float* e_e  = ws + OFF_EE;
    float* m    = ws + OFF_M;
    float* den  = ws + OFF_DEN;
    float* sx   = ws + OFF_SX;
    float* coef = ws + OFF_COEF;
    float* ft   = ws + OFF_FT;

    // zero accumulators: outputs, m (0.0f bits valid: all logits >= 0), den
    hipMemsetAsync(d_out, 0, (size_t)out_size * sizeof(float), stream);
    hipMemsetAsync(m, 0, (size_t)(N * 4 + N * 4) * sizeof(float), stream); // m + den contiguous

    k_u<<<1, 256, 0, stream>>>(Wp, attn_v, attn_e, uvT, ueT);
    k_ev<<<(N + E) / 4, 256, 0, stream>>>(vfeat, efeat, uvT, ueT, e_v, e_e);
    k_ft<<<dim3((N + 63) / 64, HD / 64), 256, 0, stream>>>(vfeat, Wv, DV2, ft);
    k_logits<<<(NNZ + 255) / 256, 256, 0, stream>>>(node_idx, edge_idx, e_v, e_e, sx, (unsigned int*)m);
    k_expsum<<<(NNZ + 255) / 256, 256, 0, stream>>>(node_idx, m, sx, den);
    k_stage1<<<NNZ / 4, 256, 0, stream>>>(node_idx, edge_idx, sx, den, ft, invDE, DV2, eout, coef);
    k_stage2<<<NNZ / 4, 256, 0, stream>>>(node_idx, edge_idx, eout, coef, vout);
}

// Round 2
// 581.579 us; speedup vs baseline: 1.3284x; 1.3284x over previous
//
#include <hip/hip_runtime.h>
#include <math.h>

namespace {
constexpr int N = 50000;
constexpr int E = 20000;
constexpr int NNZ = 800000;
constexpr int DIN = 128;
constexpr int HD = 256;   // H*DOUT

// workspace layout (float-sized slots)
constexpr size_t OFF_UVT  = 0;                            // [4][128]
constexpr size_t OFF_UET  = 512;                          // [4][128]
constexpr size_t OFF_EV   = 1024;                         // [N][4]
constexpr size_t OFF_EE   = OFF_EV  + (size_t)N * 4;      // [E][4]
constexpr size_t OFF_COEF = OFF_EE  + (size_t)E * 4;      // [NNZ]
constexpr size_t OFF_FT   = OFF_COEF+ (size_t)NNZ;        // [N][256]
constexpr size_t OFF_PTR  = OFF_FT  + (size_t)N * HD;     // int [N+1]
constexpr size_t OFF_CNT  = OFF_PTR + (size_t)(N + 1);    // int [N]  (hist, then scatter cursor)
constexpr size_t OFF_PERM = OFF_CNT + (size_t)N;          // int [NNZ]
}

// ---- kernel 1: u tables: u[h][k] = sum_d W_p[k, h*64+d] * attn[h,d] ----
__global__ void k_u(const float* __restrict__ Wp, const float* __restrict__ attn_v,
                    const float* __restrict__ attn_e,
                    float* __restrict__ uvT, float* __restrict__ ueT) {
    int t = threadIdx.x;
    for (int task = t; task < 1024; task += 256) {
        int which = task >> 9;            // 0: v-table, 1: e-table
        int hk = task & 511;
        int h = hk >> 7, k = hk & 127;
        const float* attn = which ? attn_e : attn_v;
        float s = 0.f;
        #pragma unroll 8
        for (int d = 0; d < 64; ++d)
            s += Wp[k * HD + h * 64 + d] * attn[h * 64 + d];
        (which ? ueT : uvT)[h * 128 + k] = s;
    }
}

// ---- kernel 2: e_v[n,h] = vfeat[n,:] . u_v[h,:];  e_e likewise (one wave/row)
__global__ void k_ev(const float* __restrict__ vfeat, const float* __restrict__ efeat,
                     const float* __restrict__ uvT, const float* __restrict__ ueT,
                     float* __restrict__ e_v, float* __restrict__ e_e) {
    __shared__ float su[2][4][128];
    int t = threadIdx.x;
    for (int idx = t; idx < 512; idx += 256) {
        su[0][0][idx] = uvT[idx];
        su[1][0][idx] = ueT[idx];
    }
    __syncthreads();
    int wave = t >> 6, lane = t & 63;
    int row = blockIdx.x * 4 + wave;
    if (row >= N + E) return;
    const float* feat; const float (*u)[128]; float* out; int r;
    if (row < N) { feat = vfeat; u = su[0]; out = e_v; r = row; }
    else         { feat = efeat; u = su[1]; out = e_e; r = row - N; }
    float f0 = feat[(size_t)r * DIN + lane];
    float f1 = feat[(size_t)r * DIN + 64 + lane];
    float p0 = f0 * u[0][lane] + f1 * u[0][64 + lane];
    float p1 = f0 * u[1][lane] + f1 * u[1][64 + lane];
    float p2 = f0 * u[2][lane] + f1 * u[2][64 + lane];
    float p3 = f0 * u[3][lane] + f1 * u[3][64 + lane];
    #pragma unroll
    for (int off = 32; off > 0; off >>= 1) {
        p0 += __shfl_xor(p0, off, 64);
        p1 += __shfl_xor(p1, off, 64);
        p2 += __shfl_xor(p2, off, 64);
        p3 += __shfl_xor(p3, off, 64);
    }
    if (lane == 0)
        *reinterpret_cast<float4*>(&out[(size_t)r * 4]) = make_float4(p0, p1, p2, p3);
}

// ---- kernel 3: ft = (vfeat @ W_v) * DV2, [N][256]; 64x64 tile SGEMM ----
__global__ __launch_bounds__(256) void k_ft(const float* __restrict__ vfeat,
                                            const float* __restrict__ Wv,
                                            const float* __restrict__ DV2,
                                            float* __restrict__ ft) {
    __shared__ float As[32][65];
    __shared__ float Bs[32][64];
    int tid = threadIdx.x;
    int rowBase = blockIdx.x * 64;
    int colBase = blockIdx.y * 64;
    int tx = tid & 15, ty = tid >> 4;
    int tx4 = tx * 4, ty4 = ty * 4;
    float acc[4][4] = {};
    for (int k0 = 0; k0 < DIN; k0 += 32) {
        #pragma unroll
        for (int i = 0; i < 2; ++i) {
            int e = tid + i * 256;        // 0..511
            int r = e >> 3;               // 0..63
            int k4 = e & 7;               // 0..7
            int row = rowBase + r;
            float4 v = make_float4(0.f, 0.f, 0.f, 0.f);
            if (row < N)
                v = *reinterpret_cast<const float4*>(&vfeat[(size_t)row * DIN + k0 + k4 * 4]);
            As[k4 * 4 + 0][r] = v.x;
            As[k4 * 4 + 1][r] = v.y;
            As[k4 * 4 + 2][r] = v.z;
            As[k4 * 4 + 3][r] = v.w;
        }
        #pragma unroll
        for (int i = 0; i < 2; ++i) {
            int e = tid + i * 256;
            int k = e >> 4;               // 0..31
            int c4 = e & 15;              // 0..15
            *reinterpret_cast<float4*>(&Bs[k][c4 * 4]) =
                *reinterpret_cast<const float4*>(&Wv[(size_t)(k0 + k) * HD + colBase + c4 * 4]);
        }
        __syncthreads();
        #pragma unroll 8
        for (int k = 0; k < 32; ++k) {
            float a0 = As[k][ty4 + 0], a1 = As[k][ty4 + 1];
            float a2 = As[k][ty4 + 2], a3 = As[k][ty4 + 3];
            float4 b = *reinterpret_cast<const float4*>(&Bs[k][tx4]);
            acc[0][0] += a0 * b.x; acc[0][1] += a0 * b.y; acc[0][2] += a0 * b.z; acc[0][3] += a0 * b.w;
            acc[1][0] += a1 * b.x; acc[1][1] += a1 * b.y; acc[1][2] += a1 * b.z; acc[1][3] += a1 * b.w;
            acc[2][0] += a2 * b.x; acc[2][1] += a2 * b.y; acc[2][2] += a2 * b.z; acc[2][3] += a2 * b.w;
            acc[3][0] += a3 * b.x; acc[3][1] += a3 * b.y; acc[3][2] += a3 * b.z; acc[3][3] += a3 * b.w;
        }
        __syncthreads();
    }
    #pragma unroll
    for (int mi = 0; mi < 4; ++mi) {
        int row = rowBase + ty4 + mi;
        if (row < N) {
            float dv = DV2[row];
            float4 o = make_float4(acc[mi][0] * dv, acc[mi][1] * dv,
                                   acc[mi][2] * dv, acc[mi][3] * dv);
            *reinterpret_cast<float4*>(&ft[(size_t)row * HD + colBase + tx4]) = o;
        }
    }
}

// ---- CSR build: histogram -> scan -> scatter ----
__global__ void k_hist(const int* __restrict__ node_idx, int* __restrict__ cnt) {
    int i = blockIdx.x * 256 + threadIdx.x;
    if (i < NNZ) atomicAdd(&cnt[node_idx[i]], 1);
}

__global__ __launch_bounds__(1024) void k_scan(int* __restrict__ cnt,
                                               int* __restrict__ ptr) {
    // single block; cnt is consumed and becomes the scatter cursor (= exclusive prefix)
    __shared__ int part[1024];
    int t = threadIdx.x;
    const int C = (N + 1023) / 1024;       // 49
    int lo = t * C, hi = min(lo + C, N);
    int s = 0;
    for (int i = lo; i < hi; ++i) s += cnt[i];
    part[t] = s;
    __syncthreads();
    for (int off = 1; off < 1024; off <<= 1) {
        int v = part[t];
        int add = (t >= off) ? part[t - off] : 0;
        __syncthreads();
        part[t] = v + add;
        __syncthreads();
    }
    int run = (t == 0) ? 0 : part[t - 1];
    for (int i = lo; i < hi; ++i) {
        int cv = cnt[i];
        ptr[i] = run;
        cnt[i] = run;                       // scatter cursor starts at exclusive prefix
        run += cv;
    }
    if (t == 0) ptr[N] = part[1023];
}

__global__ void k_scatter(const int* __restrict__ node_idx, int* __restrict__ cursor,
                          int* __restrict__ perm) {
    int i = blockIdx.x * 256 + threadIdx.x;
    if (i >= NNZ) return;
    int pos = atomicAdd(&cursor[node_idx[i]], 1);
    perm[pos] = i;
}

// ---- kernel 4 (merged softmax + stage 1): one wave per NODE ----
// For node n: a[i,h] = exp(s)/sum exp(s) over its incidences (s >= 0, bounded, no max
// subtraction needed); coef[i] = 0.25*(sum_h a)*invDE[e]*DV2[n];
// eout[e,d] += 0.25 * sum_h a[i,h] * ft[n, h*64+d]
__global__ __launch_bounds__(256) void k_stage1(
        const int* __restrict__ ptr, const int* __restrict__ perm,
        const int* __restrict__ edge_idx,
        const float* __restrict__ e_v, const float* __restrict__ e_e,
        const float* __restrict__ ft, const float* __restrict__ invDE,
        const float* __restrict__ DV2,
        float* __restrict__ eout, float* __restrict__ coef) {
    int n = blockIdx.x * 4 + (threadIdx.x >> 6);
    int lane = threadIdx.x & 63;
    if (n >= N) return;
    int base = ptr[n];
    int deg = ptr[n + 1] - base;
    if (deg == 0) return;

    float ev0 = e_v[(size_t)n * 4 + 0], ev1 = e_v[(size_t)n * 4 + 1];
    float ev2 = e_v[(size_t)n * 4 + 2], ev3 = e_v[(size_t)n * 4 + 3];

    // pass 1: denominators (cache chunk-0 values in registers: deg<=64 is the norm)
    float dn0 = 0.f, dn1 = 0.f, dn2 = 0.f, dn3 = 0.f;
    float x0 = 0.f, x1 = 0.f, x2 = 0.f, x3 = 0.f;
    int e0 = 0, idx0 = 0;
    for (int c = 0; c < deg; c += 64) {
        int j = c + lane;
        float t0 = 0.f, t1 = 0.f, t2 = 0.f, t3 = 0.f;
        int e = 0, idx = 0;
        if (j < deg) {
            idx = perm[base + j];
            e = edge_idx[idx];
            t0 = __expf(fmaxf(ev0 + e_e[(size_t)e * 4 + 0], 0.f));
            t1 = __expf(fmaxf(ev1 + e_e[(size_t)e * 4 + 1], 0.f));
            t2 = __expf(fmaxf(ev2 + e_e[(size_t)e * 4 + 2], 0.f));
            t3 = __expf(fmaxf(ev3 + e_e[(size_t)e * 4 + 3], 0.f));
        }
        if (c == 0) { x0 = t0; x1 = t1; x2 = t2; x3 = t3; e0 = e; idx0 = idx; }
        dn0 += t0; dn1 += t1; dn2 += t2; dn3 += t3;
    }
    #pragma unroll
    for (int off = 32; off > 0; off >>= 1) {
        dn0 += __shfl_xor(dn0, off, 64);
        dn1 += __shfl_xor(dn1, off, 64);
        dn2 += __shfl_xor(dn2, off, 64);
        dn3 += __shfl_xor(dn3, off, 64);
    }
    float r0 = 1.f / dn0, r1 = 1.f / dn1, r2 = 1.f / dn2, r3 = 1.f / dn3;

    float ft0 = ft[(size_t)n * HD + lane];
    float ft1 = ft[(size_t)n * HD + 64 + lane];
    float ft2 = ft[(size_t)n * HD + 128 + lane];
    float ft3 = ft[(size_t)n * HD + 192 + lane];
    float dv = DV2[n];

    // pass 2: coef + scatter-accumulate
    for (int c = 0; c < deg; c += 64) {
        int j = c + lane;
        float a0 = 0.f, a1 = 0.f, a2 = 0.f, a3 = 0.f;
        int e = 0;
        if (c == 0) {
            a0 = x0 * r0; a1 = x1 * r1; a2 = x2 * r2; a3 = x3 * r3;
            e = e0;
            if (j < deg)
                coef[idx0] = 0.25f * (a0 + a1 + a2 + a3) * invDE[e] * dv;
        } else if (j < deg) {
            int idx = perm[base + j];
            e = edge_idx[idx];
            a0 = __expf(fmaxf(ev0 + e_e[(size_t)e * 4 + 0], 0.f)) * r0;
            a1 = __expf(fmaxf(ev1 + e_e[(size_t)e * 4 + 1], 0.f)) * r1;
            a2 = __expf(fmaxf(ev2 + e_e[(size_t)e * 4 + 2], 0.f)) * r2;
            a3 = __expf(fmaxf(ev3 + e_e[(size_t)e * 4 + 3], 0.f)) * r3;
            coef[idx] = 0.25f * (a0 + a1 + a2 + a3) * invDE[e] * dv;
        }
        int lim = min(64, deg - c);
        for (int jj = 0; jj < lim; ++jj) {
            float b0 = __shfl(a0, jj, 64);
            float b1 = __shfl(a1, jj, 64);
            float b2 = __shfl(a2, jj, 64);
            float b3 = __shfl(a3, jj, 64);
            int   ee = __shfl(e, jj, 64);
            float v = ft0 * b0 + ft1 * b1 + ft2 * b2 + ft3 * b3;
            atomicAdd(&eout[(size_t)ee * 64 + lane], v * 0.25f);
        }
    }
}

// ---- kernel 5 (stage 2): one wave per NODE, no atomics ----
// vout[n,d] = sum_{i in inc(n)} coef[i] * eout[e_i, d]
__global__ __launch_bounds__(256) void k_stage2(
        const int* __restrict__ ptr, const int* __restrict__ perm,
        const int* __restrict__ edge_idx, const float* __restrict__ coef,
        const float* __restrict__ eout, float* __restrict__ vout) {
    int n = blockIdx.x * 4 + (threadIdx.x >> 6);
    int lane = threadIdx.x & 63;
    if (n >= N) return;
    int base = ptr[n];
    int deg = ptr[n + 1] - base;
    float acc = 0.f;
    for (int j = 0; j < deg; ++j) {
        int idx = perm[base + j];
        int e = edge_idx[idx];
        float cf = coef[idx];
        acc += cf * eout[(size_t)e * 64 + lane];
    }
    vout[(size_t)n * 64 + lane] = acc;
}

extern "C" void kernel_launch(void* const* d_in, const int* in_sizes, int n_in,
                              void* d_out, int out_size, void* d_ws, size_t ws_size,
                              hipStream_t stream) {
    const float* vfeat   = (const float*)d_in[0];
    const float* efeat   = (const float*)d_in[1];
    const float* DV2     = (const float*)d_in[2];
    const float* invDE   = (const float*)d_in[3];
    const float* Wp      = (const float*)d_in[4];
    const float* Wv      = (const float*)d_in[5];
    const float* attn_v  = (const float*)d_in[6];
    const float* attn_e  = (const float*)d_in[7];
    const int* node_idx  = (const int*)d_in[8];
    const int* edge_idx  = (const int*)d_in[9];

    float* out  = (float*)d_out;
    float* vout = out;                       // [N][64]
    float* eout = out + (size_t)N * 64;      // [E][64]

    float* ws   = (float*)d_ws;
    float* uvT  = ws + OFF_UVT;
    float* ueT  = ws + OFF_UET;
    float* e_v  = ws + OFF_EV;
    float* e_e  = ws + OFF_EE;
    float* coef = ws + OFF_COEF;
    float* ft   = ws + OFF_FT;
    int*   ptr  = (int*)(ws + OFF_PTR);
    int*   cnt  = (int*)(ws + OFF_CNT);
    int*   perm = (int*)(ws + OFF_PERM);

    // zero: eout (atomic accumulator) and the histogram counters
    hipMemsetAsync(eout, 0, (size_t)E * 64 * sizeof(float), stream);
    hipMemsetAsync(cnt, 0, (size_t)N * sizeof(int), stream);

    k_u<<<1, 256, 0, stream>>>(Wp, attn_v, attn_e, uvT, ueT);
    k_ev<<<(N + E + 3) / 4, 256, 0, stream>>>(vfeat, efeat, uvT, ueT, e_v, e_e);
    k_ft<<<dim3((N + 63) / 64, HD / 64), 256, 0, stream>>>(vfeat, Wv, DV2, ft);
    k_hist<<<(NNZ + 255) / 256, 256, 0, stream>>>(node_idx, cnt);
    k_scan<<<1, 1024, 0, stream>>>(cnt, ptr);
    k_scatter<<<(NNZ + 255) / 256, 256, 0, stream>>>(node_idx, cnt, perm);
    k_stage1<<<(N + 3) / 4, 256, 0, stream>>>(ptr, perm, edge_idx, e_v, e_e,
                                              ft, invDE, DV2, eout, coef);
    k_stage2<<<(N + 3) / 4, 256, 0, stream>>>(ptr, perm, edge_idx, coef, eout, vout);
}